// Round 6
// baseline (94.423 us; speedup 1.0000x reference)
//
#include <hip/hip_runtime.h>
#include <hip/hip_bf16.h>

// Problem constants (match reference setup_inputs)
constexpr int Bb = 64;
constexpr int T  = 4096;
constexpr int D  = 256;   // K
constexpr int A  = 10;
constexpr size_t ANCHORS_N  = (size_t)T * A * 2;         // 81920
constexpr size_t PER_TENSOR = (size_t)Bb * T * A * 2;    // 5242880
constexpr int M      = Bb * T;        // 262144 rows
constexpr int MT     = M / 16;        // 16384 m-tiles of 16 rows
constexpr int NBLK   = 1024;          // 256-thread blocks (4 waves)
constexpr int NWAVES = NBLK * 4;      // 4096 waves
constexpr int TPW    = MT / NWAVES;   // 4 tiles per wave
constexpr int NFRAG  = 24;            // 3 n-tiles x 8 k-steps

typedef __attribute__((ext_vector_type(8))) short short8v;  // 8 bf16
typedef __attribute__((ext_vector_type(4))) float f32x4;    // MFMA acc

__device__ __forceinline__ unsigned short f2b(float f) {    // RNE (pk-fusable)
    return __builtin_bit_cast(unsigned short, __float2bfloat16(f));
}

// ---- prep: anchors (blocks 0..159) + bf16 B-fragment table in d_ws (160..165)
// frag layout (R4-verified B-frag): frag[nt][ks][lane] = 8 bf16,
//   value = Wrow(nt, c=lane&15)[ (lane>>4)*8 + e + ks*32 ]   (pad cols -> 0)
__global__ void prep_k(const float* __restrict__ Wc, const float* __restrict__ Wb,
                       float* __restrict__ out_anch, unsigned short* __restrict__ wsf)
{
    const int bid = blockIdx.x;
    const int tid = threadIdx.x;
    if (bid < 160) {
        const int i = bid * 256 + tid;            // covers T*A = 40960 exactly
        const int t = i / A;
        const int a = i - t * A;
        const float L = fmaf((float)a, 160.0f / 9.0f, 40.0f);
        const float h = 0.5f * (L - 1.0f);
        reinterpret_cast<float2*>(out_anch)[i] = make_float2((float)t - h, (float)t + h);
        return;
    }
    const int f    = (bid - 160) * 4 + (tid >> 6);   // frag 0..23
    const int lane = tid & 63;
    const int nt   = f >> 3;
    const int ks   = f & 7;
    const int c    = lane & 15;
    const int kc   = lane >> 4;

    const float* wrow;
    bool pad = false;
    if (nt == 0)      wrow = Wc + c * D;
    else if (nt == 1) wrow = (c < 4) ? Wc + (16 + c) * D : Wb + (c - 4) * D;
    else { if (c < 8) wrow = Wb + (12 + c) * D; else { wrow = Wb; pad = true; } }

    const float* p = wrow + kc * 8 + ks * 32;
    short8v h;
#pragma unroll
    for (int e = 0; e < 8; ++e) h[e] = pad ? (short)0 : (short)f2b(p[e]);
    *reinterpret_cast<short8v*>(wsf + ((size_t)f * 64 + lane) * 8) = h;
}

// ---- main GEMM: [M x 256] * [256 x 48] (20 cls | 20 bbox | 8 pad), bf16 MFMA.
// x reg-staged straight from global (16 dwordx4 issued up-front per tile,
// compiler-progressive vmcnt); W-fragments read per-ks from LDS (24 KB/block).
// A-frag: lane holds A[row = lane&15][k = ks*32 + (lane>>4)*8 + e]  (R4-verified)
// C-frag: lane reg r -> C[row = (lane>>4)*4 + r][col = lane&15]
__global__ __launch_bounds__(256, 4) void rpn_main(
    const float* __restrict__ x, const unsigned short* __restrict__ wsf,
    const float* __restrict__ bc, const float* __restrict__ bb,
    float* __restrict__ out_prop, float* __restrict__ out_cls,
    float* __restrict__ out_bbox)
{
    __shared__ unsigned short wfl[NFRAG * 64 * 8];   // 24 KB

    const int tid = threadIdx.x;
    // stage fragment table (1536 float4)
    {
        const float4* src = reinterpret_cast<const float4*>(wsf);
        float4*       dst = reinterpret_cast<float4*>(wfl);
#pragma unroll
        for (int i = 0; i < 6; ++i) dst[i * 256 + tid] = src[i * 256 + tid];
    }
    __syncthreads();

    const int lane = tid & 63;
    const int wid  = blockIdx.x * 4 + (tid >> 6);
    const int c    = lane & 15;
    const int kc   = lane >> 4;

    const float bias0 = bc[c];
    const float bias1 = (c < 4) ? bc[16 + c] : bb[c - 4];
    const float bias2 = (c < 8) ? bb[12 + c] : 0.0f;

#pragma unroll 1
    for (int i = 0; i < TPW; ++i) {
        const int mt = wid + i * NWAVES;
        const float* __restrict__ xr = x + (size_t)(mt * 16 + c) * D + kc * 8;

        // issue the whole 16 KB tile (16 x dwordx4/wave) before consuming
        float4 st[16];
#pragma unroll
        for (int ch = 0; ch < 16; ++ch)
            st[ch] = *reinterpret_cast<const float4*>(xr + (ch >> 1) * 32 + (ch & 1) * 4);

        f32x4 a0 = {0,0,0,0}, a1 = {0,0,0,0}, a2 = {0,0,0,0};
#pragma unroll
        for (int ks = 0; ks < 8; ++ks) {
            const float4 qa = st[2 * ks], qb = st[2 * ks + 1];
            const float v[8] = {qa.x, qa.y, qa.z, qa.w, qb.x, qb.y, qb.z, qb.w};
            short8v xh;
#pragma unroll
            for (int e = 0; e < 8; ++e) xh[e] = (short)f2b(v[e]);

            const short8v w0 = *reinterpret_cast<const short8v*>(&wfl[((0 * 8 + ks) * 64 + lane) * 8]);
            const short8v w1 = *reinterpret_cast<const short8v*>(&wfl[((1 * 8 + ks) * 64 + lane) * 8]);
            const short8v w2 = *reinterpret_cast<const short8v*>(&wfl[((2 * 8 + ks) * 64 + lane) * 8]);
            a0 = __builtin_amdgcn_mfma_f32_16x16x32_bf16(xh, w0, a0, 0, 0, 0);
            a1 = __builtin_amdgcn_mfma_f32_16x16x32_bf16(xh, w1, a1, 0, 0, 0);
            a2 = __builtin_amdgcn_mfma_f32_16x16x32_bf16(xh, w2, a2, 0, 0, 0);
        }

        // epilogue (R4-verified): C[row = kc*4 + r][col = c]
#pragma unroll
        for (int r = 0; r < 4; ++r) {
            const int    R  = mt * 16 + kc * 4 + r;
            const size_t rb = (size_t)R * 20;

            const float v0 = a0[r] + bias0;
            out_cls[rb + c] = v0;                                // cls j = 0..15

            const float v1  = a1[r] + bias1;
            const float v1p = __shfl_xor(v1, 1);
            const float v2  = a2[r] + bias2;
            const float v2p = __shfl_xor(v2, 1);

            const int t = R & (T - 1);

            if (c < 4) {
                out_cls[rb + 16 + c] = v1;                       // cls j = 16..19
            } else {
                const int jb = c - 4;                            // bbox 0..11
                out_bbox[rb + jb] = v1;
                if (!(jb & 1)) {
                    const int   an = jb >> 1;
                    const float L  = fmaf((float)an, 160.0f / 9.0f, 40.0f);
                    const float ctr = fmaf(v1, L, (float)t);
                    const float pl  = __expf(v1p) * L;
                    const float hh  = 0.5f * (pl - 1.0f);
                    const float s = fminf(fmaxf(ctr - hh, 0.0f), (float)(T - 1));
                    const float e = fminf(fmaxf(ctr + hh, 0.0f), (float)(T - 1));
                    *reinterpret_cast<float2*>(out_prop + rb + jb) = make_float2(s, e);
                }
            }
            if (c < 8) {
                const int jb = 12 + c;                           // bbox 12..19
                out_bbox[rb + jb] = v2;
                if (!(jb & 1)) {
                    const int   an = jb >> 1;
                    const float L  = fmaf((float)an, 160.0f / 9.0f, 40.0f);
                    const float ctr = fmaf(v2, L, (float)t);
                    const float pl  = __expf(v2p) * L;
                    const float hh  = 0.5f * (pl - 1.0f);
                    const float s = fminf(fmaxf(ctr - hh, 0.0f), (float)(T - 1));
                    const float e = fminf(fmaxf(ctr + hh, 0.0f), (float)(T - 1));
                    *reinterpret_cast<float2*>(out_prop + rb + jb) = make_float2(s, e);
                }
            }
        }
    }
}

extern "C" void kernel_launch(void* const* d_in, const int* in_sizes, int n_in,
                              void* d_out, int out_size, void* d_ws, size_t ws_size,
                              hipStream_t stream) {
    const float* x  = (const float*)d_in[0];
    const float* Wc = (const float*)d_in[1];
    const float* bc = (const float*)d_in[2];
    const float* Wb = (const float*)d_in[3];
    const float* bb = (const float*)d_in[4];

    float* out     = (float*)d_out;
    float* anchors = out;
    float* prop    = out + ANCHORS_N;
    float* cls     = out + ANCHORS_N + PER_TENSOR;
    float* bbox    = out + ANCHORS_N + 2 * PER_TENSOR;

    unsigned short* wsf = (unsigned short*)d_ws;

    prep_k<<<166, 256, 0, stream>>>(Wc, Wb, anchors, wsf);
    rpn_main<<<NBLK, 256, 0, stream>>>(x, wsf, bc, bb, prop, cls, bbox);
}

// Round 7
// 80.682 us; speedup vs baseline: 1.1703x; 1.1703x over previous
//
#include <hip/hip_runtime.h>
#include <hip/hip_bf16.h>

// Problem constants (match reference setup_inputs)
constexpr int Bb = 64;
constexpr int T  = 4096;
constexpr int D  = 256;   // K
constexpr int A  = 10;
constexpr size_t ANCHORS_N  = (size_t)T * A * 2;         // 81920
constexpr size_t PER_TENSOR = (size_t)Bb * T * A * 2;    // 5242880
constexpr int M      = Bb * T;        // 262144 rows
constexpr int MT     = M / 16;        // 16384 m-tiles of 16 rows
constexpr int NBLK   = 512;           // 256-thread blocks (4 waves); 2/CU -> all resident
constexpr int NWAVES = NBLK * 4;      // 2048 waves
constexpr int TPW    = MT / NWAVES;   // 8 tiles per wave

typedef __attribute__((ext_vector_type(8))) short short8v;  // 8 bf16
typedef __attribute__((ext_vector_type(4))) float f32x4;    // MFMA acc

__device__ __forceinline__ unsigned short f2b(float f) {    // RNE (pk-fusable)
    return __builtin_bit_cast(unsigned short, __float2bfloat16(f));
}

// GEMM: [M x 256] * [256 x 48] (20 cls | 20 bbox | 8 pad), MFMA 16x16x32 bf16.
// A-frag: lane holds A[row = lane&15][k = ks*32 + (lane>>4)*8 + e]  (R4-verified)
// C-frag: lane reg r -> C[row = (lane>>4)*4 + r][col = lane&15]
//
// x staged per-wave via global_load_lds in HALF-K tiles (16 rows x 128 floats
// = 8 KB), double-buffered, counted vmcnt(8) (never 0 in steady state).
// Swizzle (rule #21, both sides): row of 32 16B-chunks; LDS[pos] = G[pos^(r&7)]
// via the per-lane global source; reads use chunk^(row&7). Compute-phase
// ds_read_b128 then spreads 8 lanes/bank-group = conflict-free floor.
__global__ __launch_bounds__(256, 2) void rpn_mfma(
    const float* __restrict__ x,
    const float* __restrict__ Wc, const float* __restrict__ bc,
    const float* __restrict__ Wb, const float* __restrict__ bb,
    float* __restrict__ out_anch, float* __restrict__ out_prop,
    float* __restrict__ out_cls,  float* __restrict__ out_bbox)
{
    __shared__ float xs[4][2][16 * 128];   // [wave][buf][16 rows x 128] = 64 KB

    const int tid  = threadIdx.x;
    const int w    = tid >> 6;
    const int lane = tid & 63;
    const int wid  = blockIdx.x * 4 + w;
    const int c    = lane & 15;   // frag col (A-row / B-col / C-col)
    const int kc   = lane >> 4;   // k-chunk 0..3

    float* const lb0 = &xs[w][0][0];
    float* const lb1 = &xs[w][1][0];

    // per-lane source offsets for the 8 staging instructions of a half-tile
    int goff[8];
    {
        const int hi5 = lane >> 5, ch = lane & 31;
#pragma unroll
        for (int i = 0; i < 8; ++i) {
            const int r = 2 * i + hi5;
            goff[i] = r * D + ((ch ^ (r & 7)) << 2);
        }
    }

    auto stage = [&](float* lbuf, int mt, int h) {
        const float* gb = x + (size_t)mt * (16 * D) + h * 128;
#pragma unroll
        for (int i = 0; i < 8; ++i) {
            __builtin_amdgcn_global_load_lds(
                (const __attribute__((address_space(1))) unsigned int*)(gb + goff[i]),
                (__attribute__((address_space(3))) unsigned int*)(lbuf + i * 256),
                16, 0, 0);
        }
    };

    // ---- per-lane weight rows + biases for the 3 N-tiles ----
    const float* wrow[3];
    float bias0, bias1, bias2;
    bool  pad2;
    wrow[0] = Wc + c * D;                       bias0 = bc[c];
    wrow[1] = (c < 4) ? Wc + (16 + c) * D : Wb + (c - 4) * D;
    bias1   = (c < 4) ? bc[16 + c] : bb[c - 4];
    if (c < 8) { wrow[2] = Wb + (12 + c) * D; bias2 = bb[12 + c]; pad2 = false; }
    else       { wrow[2] = Wb;                bias2 = 0.0f;       pad2 = true;  }

    // B fragments once per wave: wf[ntile][kstep] (96 VGPR); cvt consumption
    // drains these loads before the pipeline's counted waits begin.
    short8v wf[3][8];
#pragma unroll
    for (int nt = 0; nt < 3; ++nt) {
#pragma unroll
        for (int ks = 0; ks < 8; ++ks) {
            const float* p = wrow[nt] + kc * 8 + ks * 32;
            const float4 a = *reinterpret_cast<const float4*>(p);
            const float4 b = *reinterpret_cast<const float4*>(p + 4);
            short8v h;
            h[0] = (short)f2b(a.x); h[1] = (short)f2b(a.y);
            h[2] = (short)f2b(a.z); h[3] = (short)f2b(a.w);
            h[4] = (short)f2b(b.x); h[5] = (short)f2b(b.y);
            h[6] = (short)f2b(b.z); h[7] = (short)f2b(b.w);
            if (nt == 2 && pad2) {
#pragma unroll
                for (int e = 0; e < 8; ++e) h[e] = 0;
            }
            wf[nt][ks] = h;
        }
    }
    // force bias loads resolved before the counted-vmcnt region
    asm volatile("" : "+v"(bias0), "+v"(bias1), "+v"(bias2));

    // anchors (store issued before the staged loads -> oldest in vmcnt order)
    {
        const int i = wid * 64 + lane;           // 131072 threads cover T*A=40960
        if (i < T * A) {
            const int t = i / A;
            const int a = i - t * A;
            const float L = fmaf((float)a, 160.0f / 9.0f, 40.0f);
            const float h = 0.5f * (L - 1.0f);
            reinterpret_cast<float2*>(out_anch)[i] = make_float2((float)t - h, (float)t + h);
        }
    }

    // prologue: both halves of tile 0 in flight
    stage(lb0, wid, 0);
    stage(lb1, wid, 1);

    const int sw = (c & 7);

    auto compute_half = [&](const float* lbuf, int h, f32x4& a0, f32x4& a1, f32x4& a2) {
        const float* lrow = lbuf + c * 128;
#pragma unroll
        for (int ks = 0; ks < 4; ++ks) {
            const int ch0 = ks * 8 + kc * 2;
            const float4 qa = *reinterpret_cast<const float4*>(lrow + ((ch0 ^ sw) << 2));
            const float4 qb = *reinterpret_cast<const float4*>(lrow + (((ch0 + 1) ^ sw) << 2));
            const float v[8] = {qa.x, qa.y, qa.z, qa.w, qb.x, qb.y, qb.z, qb.w};
            short8v xh;
#pragma unroll
            for (int e = 0; e < 8; ++e) xh[e] = (short)f2b(v[e]);
            const int ksg = h * 4 + ks;
            a0 = __builtin_amdgcn_mfma_f32_16x16x32_bf16(xh, wf[0][ksg], a0, 0, 0, 0);
            a1 = __builtin_amdgcn_mfma_f32_16x16x32_bf16(xh, wf[1][ksg], a1, 0, 0, 0);
            a2 = __builtin_amdgcn_mfma_f32_16x16x32_bf16(xh, wf[2][ksg], a2, 0, 0, 0);
        }
    };

    auto epilogue = [&](int mt, const f32x4& a0, const f32x4& a1, const f32x4& a2) {
#pragma unroll
        for (int r = 0; r < 4; ++r) {
            const int    R  = mt * 16 + kc * 4 + r;
            const size_t rb = (size_t)R * 20;

            const float v0 = a0[r] + bias0;
            out_cls[rb + c] = v0;                                // cls j = 0..15

            const float v1  = a1[r] + bias1;
            const float v1p = __shfl_xor(v1, 1);
            const float v2  = a2[r] + bias2;
            const float v2p = __shfl_xor(v2, 1);

            const int t = R & (T - 1);

            if (c < 4) {
                out_cls[rb + 16 + c] = v1;                       // cls j = 16..19
            } else {
                const int jb = c - 4;                            // bbox 0..11
                out_bbox[rb + jb] = v1;
                if (!(jb & 1)) {
                    const int   an = jb >> 1;
                    const float L  = fmaf((float)an, 160.0f / 9.0f, 40.0f);
                    const float ctr = fmaf(v1, L, (float)t);
                    const float pl  = __expf(v1p) * L;
                    const float hh  = 0.5f * (pl - 1.0f);
                    const float s = fminf(fmaxf(ctr - hh, 0.0f), (float)(T - 1));
                    const float e = fminf(fmaxf(ctr + hh, 0.0f), (float)(T - 1));
                    *reinterpret_cast<float2*>(out_prop + rb + jb) = make_float2(s, e);
                }
            }
            if (c < 8) {
                const int jb = 12 + c;                           // bbox 12..19
                out_bbox[rb + jb] = v2;
                if (!(jb & 1)) {
                    const int   an = jb >> 1;
                    const float L  = fmaf((float)an, 160.0f / 9.0f, 40.0f);
                    const float ctr = fmaf(v2, L, (float)t);
                    const float pl  = __expf(v2p) * L;
                    const float hh  = 0.5f * (pl - 1.0f);
                    const float s = fminf(fmaxf(ctr - hh, 0.0f), (float)(T - 1));
                    const float e = fminf(fmaxf(ctr + hh, 0.0f), (float)(T - 1));
                    *reinterpret_cast<float2*>(out_prop + rb + jb) = make_float2(s, e);
                }
            }
        }
    };

    // steady state per tile:
    //   wait8 -> compute h0 -> stage h0(t+1) -> wait8 -> compute h1
    //   -> epilogue stores -> stage h1(t+1)
    // vmcnt retire order keeps exactly the newest 8 loads outstanding at each wait.
#pragma unroll 1
    for (int t = 0; t < TPW; ++t) {
        const int mt = wid + t * NWAVES;
        f32x4 a0 = {0,0,0,0}, a1 = {0,0,0,0}, a2 = {0,0,0,0};

        asm volatile("s_waitcnt vmcnt(8)" ::: "memory");
        __builtin_amdgcn_sched_barrier(0);
        compute_half(lb0, 0, a0, a1, a2);
        if (t + 1 < TPW) stage(lb0, wid + (t + 1) * NWAVES, 0);

        if (t + 1 < TPW) { asm volatile("s_waitcnt vmcnt(8)" ::: "memory"); }
        else             { asm volatile("s_waitcnt vmcnt(0)" ::: "memory"); }
        __builtin_amdgcn_sched_barrier(0);
        compute_half(lb1, 1, a0, a1, a2);

        epilogue(mt, a0, a1, a2);
        if (t + 1 < TPW) stage(lb1, wid + (t + 1) * NWAVES, 1);
    }
}

extern "C" void kernel_launch(void* const* d_in, const int* in_sizes, int n_in,
                              void* d_out, int out_size, void* d_ws, size_t ws_size,
                              hipStream_t stream) {
    const float* x  = (const float*)d_in[0];
    const float* Wc = (const float*)d_in[1];
    const float* bc = (const float*)d_in[2];
    const float* Wb = (const float*)d_in[3];
    const float* bb = (const float*)d_in[4];

    float* out     = (float*)d_out;
    float* anchors = out;
    float* prop    = out + ANCHORS_N;
    float* cls     = out + ANCHORS_N + PER_TENSOR;
    float* bbox    = out + ANCHORS_N + 2 * PER_TENSOR;

    rpn_mfma<<<NBLK, 256, 0, stream>>>(x, Wc, bc, Wb, bb, anchors, prop, cls, bbox);
}